// Round 6
// baseline (67.631 us; speedup 1.0000x reference)
//
#include <hip/hip_runtime.h>
#include <math.h>

// Gaussian KDE — two-level binned gather.
//
// fp32 exp(-d2/200) is exactly 0 once d2 >= ~20794 (below min denormal).
// Using margin 21000: any point with dist^2(point, voxel) >= 21000 contributes
// an exact fp32 zero, identical to the reference's own arithmetic. So culling
// by bbox distance with this cutoff is EXACT, not approximate.
//
// R4 lesson: single-kernel gather spends its time re-culling all 2048 points
// in every one of 2197 blocks (4.5M checks). Now:
//   Kernel A: 343 supertiles (2x2x2 subtiles each) cull all points once
//             (343*2048 = 0.7M checks), writing ~73 survivors/supertile to ws.
//   Kernel B: 2197 subtile blocks cull only their supertile's list
//             (~73 candidates, 1 iteration), then the 25-point phase 2.
// Overflow of a supertile list (c > CAP, ~+51 sigma, never) -> kernel B falls
// back to a direct full-point loop: still exact, just slow.

#define NXv   65
#define NYZ   (65 * 65)
#define GTOT  (65 * 65 * 65)
#define TILE  5
#define TILE3 (TILE * TILE * TILE)     // 125
#define NT    13                       // subtiles per axis
#define SG    2                        // subtiles per supertile (per axis)
#define NS    7                        // ceil(NT/SG) supertiles per axis
#define NS3   (NS * NS * NS)           // 343
#define CAP   512                      // supertile list capacity (mean ~73)
#define TPB_A 256
#define TPB_B 128
#define CUTOFF2 21000.0f

// ---------------- kernel A: bin points into supertile lists ----------------
__global__ __launch_bounds__(TPB_A)
void bin_super(const float* __restrict__ pc,     // (npts, 3)
               const float* __restrict__ tp,     // (3, 65, 65, 65)
               int*   __restrict__ counts,       // [NS3]
               float4* __restrict__ lists,       // [NS3][CAP]
               int npts) {
    __shared__ int cnt;
    const int b  = blockIdx.x;
    const int si = b / (NS * NS);
    const int r  = b - si * (NS * NS);
    const int sj = r / NS;
    const int sk = r - sj * NS;

    // voxel-index span of this supertile (last super per axis is smaller)
    const int i0 = si * SG * TILE, i1 = min(i0 + SG * TILE - 1, NXv - 1);
    const int j0 = sj * SG * TILE, j1 = min(j0 + SG * TILE - 1, NXv - 1);
    const int k0 = sk * SG * TILE, k1 = min(k0 + SG * TILE - 1, NXv - 1);

    // axis coords straight from target_points (bit-identical to JAX linspace)
    const float xmin = tp[(size_t)i0 * NYZ];
    const float xmax = tp[(size_t)i1 * NYZ];
    const float ymin = tp[GTOT + (size_t)j0 * NXv];
    const float ymax = tp[GTOT + (size_t)j1 * NXv];
    const float zmin = tp[2 * GTOT + k0];
    const float zmax = tp[2 * GTOT + k1];

    if (threadIdx.x == 0) cnt = 0;
    __syncthreads();

    for (int i = threadIdx.x; i < npts; i += TPB_A) {
        const float px = pc[3 * i + 0];
        const float py = pc[3 * i + 1];
        const float pz = pc[3 * i + 2];
        const float dx = fmaxf(fmaxf(xmin - px, px - xmax), 0.0f);
        const float dy = fmaxf(fmaxf(ymin - py, py - ymax), 0.0f);
        const float dz = fmaxf(fmaxf(zmin - pz, pz - zmax), 0.0f);
        if (dx * dx + dy * dy + dz * dz < CUTOFF2) {
            const int pos = atomicAdd(&cnt, 1);   // LDS atomic
            if (pos < CAP) lists[(size_t)b * CAP + pos] = make_float4(px, py, pz, 0.0f);
        }
    }
    __syncthreads();
    if (threadIdx.x == 0) counts[b] = cnt;   // written for ALL supers (un-poisons)
}

// ---------------- kernel B: per-subtile gather from supertile list ----------
__global__ __launch_bounds__(TPB_B)
void kde_tile(const float* __restrict__ pc,      // (npts, 3) — fallback only
              const float* __restrict__ tp,      // (3, 65, 65, 65)
              const int*   __restrict__ counts,
              const float4* __restrict__ lists,
              float* __restrict__ out,           // (65, 65, 65)
              int npts) {
    __shared__ float sx[CAP], sy[CAP], sz[CAP];  // 6 KB
    __shared__ float axs[3][TILE];
    __shared__ int   cnt;

    const int tid = threadIdx.x;
    const int bt  = blockIdx.x;
    const int ti  = bt / (NT * NT);
    const int rm  = bt - ti * (NT * NT);
    const int tj  = rm / NT;
    const int tk  = rm - tj * NT;
    const int i0  = ti * TILE, j0 = tj * TILE, k0 = tk * TILE;
    const int sb  = (ti / SG) * (NS * NS) + (tj / SG) * NS + (tk / SG);

    if (tid == 0) cnt = 0;
    if (tid < 3 * TILE) {
        const int axis = tid / TILE;
        const int off  = tid - axis * TILE;
        const int idx  = ((axis == 0) ? i0 : (axis == 1) ? j0 : k0) + off;
        const int strd = (axis == 0) ? NYZ : (axis == 1) ? NXv : 1;
        axs[axis][off] = tp[(size_t)axis * GTOT + (size_t)idx * strd];
    }
    __syncthreads();

    const float xmin = axs[0][0], xmax = axs[0][TILE - 1];
    const float ymin = axs[1][0], ymax = axs[1][TILE - 1];
    const float zmin = axs[2][0], zmax = axs[2][TILE - 1];

    const int  c      = counts[sb];
    const bool direct = (c > CAP);   // pathological overflow -> exact fallback

    if (!direct) {
        // cull supertile candidates (~73) against subtile bbox; <=1 iteration
        for (int p = tid; p < c; p += TPB_B) {
            const float4 q = lists[(size_t)sb * CAP + p];   // coalesced 16B
            const float dx = fmaxf(fmaxf(xmin - q.x, q.x - xmax), 0.0f);
            const float dy = fmaxf(fmaxf(ymin - q.y, q.y - ymax), 0.0f);
            const float dz = fmaxf(fmaxf(zmin - q.z, q.z - zmax), 0.0f);
            if (dx * dx + dy * dy + dz * dz < CUTOFF2) {
                const int pos = atomicAdd(&cnt, 1);   // pos < c <= CAP, safe
                sx[pos] = q.x; sy[pos] = q.y; sz[pos] = q.z;
            }
        }
    }
    __syncthreads();
    const int np = cnt;

    // exp(-d2/200) == exp2(d2 * -log2(e)/200); constant folded in double.
    const float kneg     = (float)(-1.4426950408889634 / 200.0);
    const float inv_norm = 1.0f / (2.0f * 3.14159274101257324f * 100.0f);

    if (tid < TILE3) {
        const int li = tid / (TILE * TILE);
        const int r2 = tid - li * (TILE * TILE);
        const int lj = r2 / TILE;
        const int lk = r2 - lj * TILE;
        const float vx = axs[0][li];
        const float vy = axs[1][lj];
        const float vz = axs[2][lk];
        float acc = 0.0f;
        if (!direct) {
            #pragma unroll 4
            for (int p = 0; p < np; ++p) {
                const float dx = vx - sx[p];   // LDS broadcast reads
                const float dy = vy - sy[p];
                const float dz = vz - sz[p];
                const float d2 = fmaf(dx, dx, fmaf(dy, dy, dz * dz));
                acc += exp2f(d2 * kneg);       // far pairs underflow to exact 0
            }
        } else {
            for (int p = 0; p < npts; ++p) {   // exact fallback, never expected
                const float dx = vx - pc[3 * p + 0];
                const float dy = vy - pc[3 * p + 1];
                const float dz = vz - pc[3 * p + 2];
                const float d2 = fmaf(dx, dx, fmaf(dy, dy, dz * dz));
                acc += exp2f(d2 * kneg);
            }
        }
        out[(i0 + li) * NYZ + (j0 + lj) * NXv + (k0 + lk)] = acc * inv_norm;
    }
}

extern "C" void kernel_launch(void* const* d_in, const int* in_sizes, int n_in,
                              void* d_out, int out_size, void* d_ws, size_t ws_size,
                              hipStream_t stream) {
    const float* pc  = (const float*)d_in[0];   // pointcloud (N, 3)
    const float* tp  = (const float*)d_in[1];   // target_points (3, 65, 65, 65)
    float*       out = (float*)d_out;           // (65, 65, 65) fp32

    const int npts = in_sizes[0] / 3;

    // ws layout: counts[NS3] at +0; lists[NS3][CAP] float4 at +4096.
    int*    counts = (int*)d_ws;
    float4* lists  = (float4*)((char*)d_ws + 4096);

    bin_super<<<NS3, TPB_A, 0, stream>>>(pc, tp, counts, lists, npts);
    kde_tile<<<NT * NT * NT, TPB_B, 0, stream>>>(pc, tp, counts, lists, out, npts);
}